// Round 3
// baseline (539.890 us; speedup 1.0000x reference)
//
#include <hip/hip_runtime.h>

#define DD 768
#define HDIM 96
#define ATT_SCALE 0.10206207261596575f  // 1/sqrt(96)

typedef float floatx4 __attribute__((ext_vector_type(4)));
typedef __bf16 bf16;
typedef bf16 bf16x8 __attribute__((ext_vector_type(8)));
typedef bf16 bf16x4 __attribute__((ext_vector_type(4)));

__device__ __forceinline__ void gl2lds16(const bf16* g, bf16* l) {
  __builtin_amdgcn_global_load_lds(
      (const __attribute__((address_space(1))) void*)g,
      (__attribute__((address_space(3))) void*)l, 16, 0, 0);
}

// ------------------------------------------------ conversions (fp32 -> bf16)
__global__ __launch_bounds__(256) void conv_fuse(const float* __restrict__ f,
                                                 const float* __restrict__ e,
                                                 bf16* __restrict__ fb,
                                                 bf16* __restrict__ xb,
                                                 bf16* __restrict__ eb) {
  const int i = (blockIdx.x * 256 + threadIdx.x) * 8;
  floatx4 f0 = *(const floatx4*)(f + i);
  floatx4 f1 = *(const floatx4*)(f + i + 4);
  floatx4 e0 = *(const floatx4*)(e + i);
  floatx4 e1 = *(const floatx4*)(e + i + 4);
  bf16x8 fv, xv, ev;
#pragma unroll
  for (int k = 0; k < 4; k++) {
    fv[k] = (bf16)f0[k];           fv[k + 4] = (bf16)f1[k];
    ev[k] = (bf16)e0[k];           ev[k + 4] = (bf16)e1[k];
    xv[k] = (bf16)(f0[k] + e0[k]); xv[k + 4] = (bf16)(f1[k] + e1[k]);
  }
  *(bf16x8*)(fb + i) = fv;
  *(bf16x8*)(xb + i) = xv;
  *(bf16x8*)(eb + i) = ev;
}

__global__ __launch_bounds__(256) void f2b(const float* __restrict__ s,
                                           bf16* __restrict__ d) {
  const int i = (blockIdx.x * 256 + threadIdx.x) * 8;
  floatx4 s0 = *(const floatx4*)(s + i);
  floatx4 s1 = *(const floatx4*)(s + i + 4);
  bf16x8 v;
#pragma unroll
  for (int k = 0; k < 4; k++) { v[k] = (bf16)s0[k]; v[k + 4] = (bf16)s1[k]; }
  *(bf16x8*)(d + i) = v;
}

__global__ __launch_bounds__(256) void wconv(const float* w0, const float* w1,
                                             const float* w2, const float* w3,
                                             const float* w4, const float* w5,
                                             const float* w6, const float* w7,
                                             bf16* __restrict__ dst) {
  const float* srcs[8] = {w0, w1, w2, w3, w4, w5, w6, w7};
  const float* s = srcs[blockIdx.y];
  bf16* d = dst + (size_t)blockIdx.y * 589824;
  const int i = (blockIdx.x * 256 + threadIdx.x) * 8;
  floatx4 s0 = *(const floatx4*)(s + i);
  floatx4 s1 = *(const floatx4*)(s + i + 4);
  bf16x8 v;
#pragma unroll
  for (int k = 0; k < 4; k++) { v[k] = (bf16)s0[k]; v[k + 4] = (bf16)s1[k]; }
  *(bf16x8*)(d + i) = v;
}

// ------------------------------------------------ batched LayerNorm (bf16, in place)
__device__ __forceinline__ void ln_row(bf16* x, const float* g, int lane) {
  float v[12], s = 0.f, ss = 0.f;
#pragma unroll
  for (int j = 0; j < 3; j++) {
    bf16x4 b = *(const bf16x4*)&x[j * 256 + lane * 4];
#pragma unroll
    for (int e = 0; e < 4; e++) {
      float t = (float)b[e];
      v[j * 4 + e] = t; s += t; ss += t * t;
    }
  }
#pragma unroll
  for (int o = 32; o > 0; o >>= 1) { s += __shfl_xor(s, o); ss += __shfl_xor(ss, o); }
  const float mean = s * (1.0f / DD);
  const float inv = rsqrtf(ss * (1.0f / DD) - mean * mean + 1e-6f);
#pragma unroll
  for (int j = 0; j < 3; j++) {
    floatx4 gg = *(const floatx4*)&g[j * 256 + lane * 4];
    bf16x4 o4;
#pragma unroll
    for (int e = 0; e < 4; e++) o4[e] = (bf16)((v[j * 4 + e] - mean) * inv * gg[e]);
    *(bf16x4*)&x[j * 256 + lane * 4] = o4;
  }
}

// segments: X0 16384 rows, X1 16384 rows, X2 4096 rows, X3 4096 rows (4 rows/block)
__global__ __launch_bounds__(256) void ln_all(bf16* X0, const float* g0,
                                              bf16* X1, const float* g1,
                                              bf16* X2, const float* g2,
                                              bf16* X3, const float* g3) {
  const int b = blockIdx.x;
  bf16* X; const float* g; int base;
  if (b < 4096)      { X = X0; g = g0; base = b; }
  else if (b < 8192) { X = X1; g = g1; base = b - 4096; }
  else if (b < 9216) { X = X2; g = g2; base = b - 8192; }
  else               { X = X3; g = g3; base = b - 9216; }
  const int w = threadIdx.x >> 6, lane = threadIdx.x & 63;
  ln_row(X + (size_t)(base * 4 + w) * DD, g, lane);
}

// ------------------------------------------------ GEMM core  C = A @ W^T  (m97 structure)
// 128x128 tile, BK=32, global_load_lds w16, unpadded LDS. MODE 0: C bf16. MODE 1: fp32+add.
template <int MODE>
__device__ __forceinline__ void gemm_core(const bf16* __restrict__ A,
                                          const bf16* __restrict__ W,
                                          bf16* __restrict__ Cb,
                                          float* __restrict__ Cf,
                                          const float* __restrict__ addsrc,
                                          bf16* As, bf16* Ws) {
  const int tid = threadIdx.x;
  const int lane = tid & 63;
  const int w = tid >> 6;
  const int row0 = blockIdx.x * 128;
  const int col0 = blockIdx.y * 128;
  const int wm = (w & 1) * 64;
  const int wn = (w >> 1) * 64;
  const int fr = lane & 15;
  const int quad = lane >> 4;
  const int srow = tid >> 2;
  const int scol = (tid & 3) * 8;
  const bf16* Ag = A + (size_t)(row0 + srow) * DD + scol;
  const bf16* Wg = W + (size_t)(col0 + srow) * DD + scol;
  bf16* AsD = &As[tid * 8];
  bf16* WsD = &Ws[tid * 8];

  floatx4 acc[4][4];
#pragma unroll
  for (int i = 0; i < 4; i++)
#pragma unroll
    for (int j = 0; j < 4; j++) acc[i][j] = (floatx4){0, 0, 0, 0};

  for (int k0 = 0; k0 < DD; k0 += 32) {
    __syncthreads();
    gl2lds16(Ag + k0, AsD);
    gl2lds16(Ag + k0 + (size_t)64 * DD, AsD + 2048);
    gl2lds16(Wg + k0, WsD);
    gl2lds16(Wg + k0 + (size_t)64 * DD, WsD + 2048);
    __syncthreads();
    bf16x8 af[4], bfr[4];
#pragma unroll
    for (int i = 0; i < 4; i++)
      af[i] = *(const bf16x8*)&As[(wm + i * 16 + fr) * 32 + quad * 8];
#pragma unroll
    for (int j = 0; j < 4; j++)
      bfr[j] = *(const bf16x8*)&Ws[(wn + j * 16 + fr) * 32 + quad * 8];
#pragma unroll
    for (int i = 0; i < 4; i++)
#pragma unroll
      for (int j = 0; j < 4; j++)
        acc[i][j] = __builtin_amdgcn_mfma_f32_16x16x32_bf16(af[i], bfr[j], acc[i][j], 0, 0, 0);
  }
#pragma unroll
  for (int i = 0; i < 4; i++)
#pragma unroll
    for (int j = 0; j < 4; j++)
#pragma unroll
      for (int r = 0; r < 4; r++) {
        const int row = row0 + wm + i * 16 + quad * 4 + r;
        const int col = col0 + wn + j * 16 + fr;
        const size_t idx = (size_t)row * DD + col;
        if (MODE == 0) Cb[idx] = (bf16)acc[i][j][r];
        else Cf[idx] = acc[i][j][r] + addsrc[idx];
      }
}

__global__ __launch_bounds__(256) void gemm_b(const bf16* A, const bf16* W, bf16* C) {
  __shared__ bf16 As[4096], Ws[4096];
  gemm_core<0>(A, W, C, nullptr, nullptr, As, Ws);
}

__global__ __launch_bounds__(256) void gemm_b2(const bf16* A0, const bf16* W0, bf16* C0,
                                               const bf16* A1, const bf16* W1, bf16* C1) {
  __shared__ bf16 As[4096], Ws[4096];
  if (blockIdx.z == 0) gemm_core<0>(A0, W0, C0, nullptr, nullptr, As, Ws);
  else                 gemm_core<0>(A1, W1, C1, nullptr, nullptr, As, Ws);
}

__global__ __launch_bounds__(256) void gemm_final(const bf16* A, const bf16* W,
                                                  float* C, const float* addsrc) {
  __shared__ bf16 As[4096], Ws[4096];
  gemm_core<1>(A, W, nullptr, C, addsrc, As, Ws);
}

// ------------------------------------------------ fused attention
// RPW: 16-row tiles per wave (block covers 64*RPW queries).
// SPLIT: flash-decoding partial mode (writes normalized partial O + per-row m,l).
// grid decode: b = (sp*nqt + qt)*128 + t*8 + h   (same-h blocks share an XCD slice)
template <int RPW, int SPLIT>
__global__ __launch_bounds__(256) void attn_kernel(
    const bf16* __restrict__ Qb, const bf16* __restrict__ Kb,
    const bf16* __restrict__ Vb, bf16* __restrict__ Ob,
    float* __restrict__ Ml,
    const float* __restrict__ qpos, int qpos_ts,
    const float* __restrict__ kpos, int kpos_ts,
    int nq, int nk, int nqt, int nsp) {
  const int b = blockIdx.x;
  const int h = b & 7;
  const int t = (b >> 3) & 15;
  const int rest = b >> 7;
  const int qt = rest % nqt;
  const int sp = rest / nqt;
  const int klen = nk / nsp;
  const int k0s = sp * klen;
  const int q0 = qt * (64 * RPW);
  const bf16* Q = Qb + (size_t)t * nq * DD + h * HDIM;
  const bf16* K = Kb + (size_t)t * nk * DD + h * HDIM;
  const bf16* V = Vb + (size_t)t * nk * DD + h * HDIM;
  bf16* O = Ob + (size_t)(SPLIT ? (sp * 16 + t) : t) * nq * DD + h * HDIM;
  const float* qp = qpos + (size_t)t * qpos_ts;
  const float* kp = kpos + (size_t)t * kpos_ts;

  __shared__ bf16 Ks[64 * 104];        // [n][k] stride 104
  __shared__ bf16 Vt[96 * 72];         // [d][n] stride 72
  __shared__ bf16 Ps[RPW * 64 * 72];   // [m][n]

  const int tid = threadIdx.x;
  const int w = tid >> 6;
  const int lane = tid & 63;
  const int fr = lane & 15;
  const int quad = lane >> 4;
  const int rowb = w * (16 * RPW);

  bf16x8 qf[RPW][3];
  float qx[RPW][4], qy[RPW][4];
#pragma unroll
  for (int rt = 0; rt < RPW; rt++) {
    const bf16* qrow = Q + (size_t)(q0 + rowb + rt * 16 + fr) * DD;
#pragma unroll
    for (int c = 0; c < 3; c++) qf[rt][c] = *(const bf16x8*)(qrow + c * 32 + quad * 8);
#pragma unroll
    for (int r = 0; r < 4; r++) {
      int qi = q0 + rowb + rt * 16 + quad * 4 + r;
      qx[rt][r] = qp[qi * 2];
      qy[rt][r] = qp[qi * 2 + 1];
    }
  }

  float mrow[RPW][4], lrow[RPW][4];
  floatx4 oacc[RPW][6];
#pragma unroll
  for (int rt = 0; rt < RPW; rt++) {
#pragma unroll
    for (int r = 0; r < 4; r++) { mrow[rt][r] = -1e30f; lrow[rt][r] = 0.f; }
#pragma unroll
    for (int d = 0; d < 6; d++) oacc[rt][d] = (floatx4){0, 0, 0, 0};
  }

  const int srow = tid >> 2, scol = (tid & 3) * 24;
  const int nb = (tid & 15) * 4, db = (tid >> 4) * 6;

  for (int n0 = k0s; n0 < k0s + klen; n0 += 64) {
    __syncthreads();
    {  // K tile [64][96]
      const bf16* kg = K + (size_t)(n0 + srow) * DD + scol;
      bf16* ks = &Ks[srow * 104 + scol];
#pragma unroll
      for (int c = 0; c < 3; c++) *(bf16x8*)(ks + c * 8) = *(const bf16x8*)(kg + c * 8);
    }
    {  // V tile transposed: thread covers 4 n x 6 d, b64 LDS writes
      bf16 tmp[4][6];
#pragma unroll
      for (int nn = 0; nn < 4; nn++) {
        const unsigned* vg = (const unsigned*)(V + (size_t)(n0 + nb + nn) * DD + db);
        unsigned u0 = vg[0], u1 = vg[1], u2 = vg[2];
        *(unsigned*)&tmp[nn][0] = u0;
        *(unsigned*)&tmp[nn][2] = u1;
        *(unsigned*)&tmp[nn][4] = u2;
      }
#pragma unroll
      for (int dd = 0; dd < 6; dd++) {
        bf16x4 v4 = {tmp[0][dd], tmp[1][dd], tmp[2][dd], tmp[3][dd]};
        *(bf16x4*)&Vt[(db + dd) * 72 + nb] = v4;
      }
    }
    __syncthreads();

    float kxx[4], kyy[4];
#pragma unroll
    for (int j = 0; j < 4; j++) {
      int ki = (n0 + j * 16 + fr) * 2;
      kxx[j] = kp[ki];
      kyy[j] = kp[ki + 1];
    }

#pragma unroll
    for (int rt = 0; rt < RPW; rt++) {
      floatx4 s4[4];
#pragma unroll
      for (int j = 0; j < 4; j++) {
        floatx4 sa = {0, 0, 0, 0};
#pragma unroll
        for (int c = 0; c < 3; c++) {
          bf16x8 kf = *(const bf16x8*)&Ks[(j * 16 + fr) * 104 + c * 32 + quad * 8];
          sa = __builtin_amdgcn_mfma_f32_16x16x32_bf16(qf[rt][c], kf, sa, 0, 0, 0);
        }
        s4[j] = sa;
      }
      float p[4][4], rmax[4], rsum[4], alpha[4];
#pragma unroll
      for (int r = 0; r < 4; r++) rmax[r] = -1e30f;
#pragma unroll
      for (int j = 0; j < 4; j++)
#pragma unroll
        for (int r = 0; r < 4; r++) {
          float dx = qx[rt][r] - kxx[j], dy = qy[rt][r] - kyy[j];
          float sv = s4[j][r] * ATT_SCALE - 2.0f * (dx * dx + dy * dy);
          p[j][r] = sv;
          rmax[r] = fmaxf(rmax[r], sv);
        }
#pragma unroll
      for (int r = 0; r < 4; r++) {
#pragma unroll
        for (int o = 1; o < 16; o <<= 1) rmax[r] = fmaxf(rmax[r], __shfl_xor(rmax[r], o));
        float mnew = fmaxf(mrow[rt][r], rmax[r]);
        alpha[r] = __expf(mrow[rt][r] - mnew);
        mrow[rt][r] = mnew;
        rsum[r] = 0.f;
      }
#pragma unroll
      for (int j = 0; j < 4; j++)
#pragma unroll
        for (int r = 0; r < 4; r++) {
          float pv = __expf(p[j][r] - mrow[rt][r]);
          p[j][r] = pv;
          rsum[r] += pv;
        }
#pragma unroll
      for (int r = 0; r < 4; r++) {
#pragma unroll
        for (int o = 1; o < 16; o <<= 1) rsum[r] += __shfl_xor(rsum[r], o);
        lrow[rt][r] = lrow[rt][r] * alpha[r] + rsum[r];
      }
#pragma unroll
      for (int j = 0; j < 4; j++)
#pragma unroll
        for (int r = 0; r < 4; r++)
          Ps[(rowb + rt * 16 + quad * 4 + r) * 72 + j * 16 + fr] = (bf16)p[j][r];
#pragma unroll
      for (int d = 0; d < 6; d++)
#pragma unroll
        for (int r = 0; r < 4; r++) oacc[rt][d][r] *= alpha[r];
    }

    // PV: read P (A-layout) + Vt (B-layout); V frags shared across row-tiles
    bf16x8 pf[RPW][2];
#pragma unroll
    for (int rt = 0; rt < RPW; rt++) {
      pf[rt][0] = *(const bf16x8*)&Ps[(rowb + rt * 16 + fr) * 72 + quad * 8];
      pf[rt][1] = *(const bf16x8*)&Ps[(rowb + rt * 16 + fr) * 72 + 32 + quad * 8];
    }
#pragma unroll
    for (int d = 0; d < 6; d++) {
      bf16x8 v0 = *(const bf16x8*)&Vt[(d * 16 + fr) * 72 + quad * 8];
      bf16x8 v1 = *(const bf16x8*)&Vt[(d * 16 + fr) * 72 + 32 + quad * 8];
#pragma unroll
      for (int rt = 0; rt < RPW; rt++) {
        oacc[rt][d] = __builtin_amdgcn_mfma_f32_16x16x32_bf16(pf[rt][0], v0, oacc[rt][d], 0, 0, 0);
        oacc[rt][d] = __builtin_amdgcn_mfma_f32_16x16x32_bf16(pf[rt][1], v1, oacc[rt][d], 0, 0, 0);
      }
    }
  }

#pragma unroll
  for (int rt = 0; rt < RPW; rt++)
#pragma unroll
    for (int r = 0; r < 4; r++) {
      float inv = 1.0f / lrow[rt][r];
      int row = q0 + rowb + rt * 16 + quad * 4 + r;
#pragma unroll
      for (int d = 0; d < 6; d++)
        O[(size_t)row * DD + d * 16 + fr] = (bf16)(oacc[rt][d][r] * inv);
      if (SPLIT && fr == 0) {
        size_t mi = ((((size_t)sp * 16 + t) * 8 + h) * nq + row) * 2;
        Ml[mi] = mrow[rt][r];
        Ml[mi + 1] = lrow[rt][r];
      }
    }
}

// combine 2 split partials: Out = (w0*O0 + w1*O1)/(w0+w1), w_i = l_i e^{m_i-m}
__global__ __launch_bounds__(256) void combine2(const bf16* __restrict__ Op,
                                                const float* __restrict__ Ml,
                                                bf16* __restrict__ Out) {
  const int row = blockIdx.x;  // t*256 + q
  const int t = row >> 8;
  const int q = row & 255;
  const size_t half = (size_t)16 * 256 * DD;
#pragma unroll
  for (int e = 0; e < 3; e++) {
    int dim = threadIdx.x + e * 256;
    int hh = dim / 96;
    size_t mi0 = (((size_t)t * 8 + hh) * 256 + q) * 2;
    size_t mi1 = ((((size_t)16 + t) * 8 + hh) * 256 + q) * 2;
    float m0 = Ml[mi0], l0 = Ml[mi0 + 1];
    float m1 = Ml[mi1], l1 = Ml[mi1 + 1];
    float mm = fmaxf(m0, m1);
    float w0 = __expf(m0 - mm) * l0, w1 = __expf(m1 - mm) * l1;
    float inv = 1.0f / (w0 + w1);
    size_t idx = (size_t)row * DD + dim;
    Out[idx] = (bf16)((w0 * (float)Op[idx] + w1 * (float)Op[idx + half]) * inv);
  }
}

// ------------------------------------------------ launch
extern "C" void kernel_launch(void* const* d_in, const int* in_sizes, int n_in,
                              void* d_out, int out_size, void* d_ws, size_t ws_size,
                              hipStream_t stream) {
  const float* features = (const float*)d_in[0];
  const float* tracks   = (const float*)d_in[1];
  const float* fpos     = (const float*)d_in[2];
  const float* tpe      = (const float*)d_in[3];
  const float* fpe      = (const float*)d_in[4];
  const float* Wq_s     = (const float*)d_in[5];
  const float* Wk_s     = (const float*)d_in[6];
  const float* Wv_s     = (const float*)d_in[7];
  const float* qg_s     = (const float*)d_in[8];
  const float* kg_s     = (const float*)d_in[9];
  const float* Wo_s     = (const float*)d_in[10];
  const float* Wq_p     = (const float*)d_in[11];
  const float* Wk_p     = (const float*)d_in[12];
  const float* Wv_p     = (const float*)d_in[13];
  const float* qg_p     = (const float*)d_in[14];
  const float* kg_p     = (const float*)d_in[15];
  const float* Wout_p   = (const float*)d_in[16];
  float* out = (float*)d_out;

  const size_t SB = (size_t)16 * 1024 * 768;
  const size_t SS = (size_t)16 * 256 * 768;
  const size_t SW = (size_t)768 * 768;
  bf16* p = (bf16*)d_ws;
  bf16* Fb  = p; p += SB;     // features bf16 (later reused as U)
  bf16* Xb  = p; p += SB;     // features+fpe (later reused as Q2)
  bf16* Feb = p; p += SB;     // fpe bf16
  bf16* Kc  = p; p += SB;     // K_s
  bf16* Vc  = p; p += SB;     // V_s
  bf16* Tb  = p; p += SS;     // tpe bf16
  bf16* Qc  = p; p += SS;     // Q_s
  bf16* K2  = p; p += SS;     // K2
  bf16* Sh  = p; p += SS;     // sampled heads (later reused as V2)
  bf16* Sp  = p; p += SS;     // sampled
  bf16* Op  = p; p += 2 * SS; // split-K partial O
  bf16* Wb  = p; p += 8 * SW; // weights bf16
  float* Ml = (float*)p;      // split-K (m,l): 2*16*8*256*2 floats
  bf16* Q2 = Xb; bf16* V2 = Sh; bf16* U = Fb;

  dim3 blk(256);

  conv_fuse<<<6144, blk, 0, stream>>>(features, fpe, Fb, Xb, Feb);
  f2b<<<1536, blk, 0, stream>>>(tpe, Tb);
  wconv<<<dim3(288, 8), blk, 0, stream>>>(Wq_s, Wk_s, Wv_s, Wo_s,
                                          Wq_p, Wk_p, Wv_p, Wout_p, Wb);
  // big GEMMs: K_s and V_s batched; Q2 after (frees Xb aliasing hazard)
  gemm_b2<<<dim3(128, 6, 2), blk, 0, stream>>>(Xb, Wb + 1 * SW, Kc,
                                               Fb, Wb + 2 * SW, Vc);
  gemm_b<<<dim3(128, 6), blk, 0, stream>>>(Feb, Wb + 4 * SW, Q2);
  // small GEMMs: Q_s and K2 batched
  gemm_b2<<<dim3(32, 6, 2), blk, 0, stream>>>(Tb, Wb + 0 * SW, Qc,
                                              Tb, Wb + 5 * SW, K2);
  // all four LayerNorms in one launch
  ln_all<<<10240, blk, 0, stream>>>(Kc, kg_s, Q2, qg_p, Qc, qg_s, K2, kg_p);
  // sampling attention: tracks query pixels, split-K x2 (nq=256, nk=1024)
  attn_kernel<1, 1><<<1024, blk, 0, stream>>>(Qc, Kc, Vc, Op, Ml,
                                              tracks, 512, fpos, 0, 256, 1024, 4, 2);
  combine2<<<4096, blk, 0, stream>>>(Op, Ml, Sh);
  gemm_b<<<dim3(32, 6), blk, 0, stream>>>(Sh, Wb + 3 * SW, Sp);
  gemm_b<<<dim3(32, 6), blk, 0, stream>>>(Sp, Wb + 6 * SW, V2);
  // splatting attention: pixels query tracks, QTILE=128 (nq=1024, nk=256)
  attn_kernel<2, 0><<<1024, blk, 0, stream>>>(Q2, K2, V2, U, nullptr,
                                              fpos, 0, tracks, 512, 1024, 256, 8, 1);
  gemm_final<<<dim3(128, 6), blk, 0, stream>>>(U, Wb + 7 * SW, out, features);
}

// Round 4
// 491.420 us; speedup vs baseline: 1.0986x; 1.0986x over previous
//
#include <hip/hip_runtime.h>

#define DD 768
#define HDIM 96
#define ATT_SCALE 0.10206207261596575f  // 1/sqrt(96)

typedef float floatx4 __attribute__((ext_vector_type(4)));
typedef __bf16 bf16;
typedef bf16 bf16x8 __attribute__((ext_vector_type(8)));
typedef bf16 bf16x4 __attribute__((ext_vector_type(4)));
typedef bf16 bf16x2 __attribute__((ext_vector_type(2)));

__device__ __forceinline__ void gl2lds16(const bf16* g, bf16* l) {
  __builtin_amdgcn_global_load_lds(
      (const __attribute__((address_space(1))) void*)g,
      (__attribute__((address_space(3))) void*)l, 16, 0, 0);
}

// ------------------------------------------------ conversions (fp32 -> bf16)
__global__ __launch_bounds__(256) void conv_fuse(const float* __restrict__ f,
                                                 const float* __restrict__ e,
                                                 bf16* __restrict__ fb,
                                                 bf16* __restrict__ xb,
                                                 bf16* __restrict__ eb) {
  const int i = (blockIdx.x * 256 + threadIdx.x) * 8;
  floatx4 f0 = *(const floatx4*)(f + i);
  floatx4 f1 = *(const floatx4*)(f + i + 4);
  floatx4 e0 = *(const floatx4*)(e + i);
  floatx4 e1 = *(const floatx4*)(e + i + 4);
  bf16x8 fv, xv, ev;
#pragma unroll
  for (int k = 0; k < 4; k++) {
    fv[k] = (bf16)f0[k];           fv[k + 4] = (bf16)f1[k];
    ev[k] = (bf16)e0[k];           ev[k + 4] = (bf16)e1[k];
    xv[k] = (bf16)(f0[k] + e0[k]); xv[k + 4] = (bf16)(f1[k] + e1[k]);
  }
  *(bf16x8*)(fb + i) = fv;
  *(bf16x8*)(xb + i) = xv;
  *(bf16x8*)(eb + i) = ev;
}

__global__ __launch_bounds__(256) void f2b(const float* __restrict__ s,
                                           bf16* __restrict__ d) {
  const int i = (blockIdx.x * 256 + threadIdx.x) * 8;
  floatx4 s0 = *(const floatx4*)(s + i);
  floatx4 s1 = *(const floatx4*)(s + i + 4);
  bf16x8 v;
#pragma unroll
  for (int k = 0; k < 4; k++) { v[k] = (bf16)s0[k]; v[k + 4] = (bf16)s1[k]; }
  *(bf16x8*)(d + i) = v;
}

__global__ __launch_bounds__(256) void wconv(const float* w0, const float* w1,
                                             const float* w2, const float* w3,
                                             const float* w4, const float* w5,
                                             const float* w6, const float* w7,
                                             bf16* __restrict__ dst) {
  const float* srcs[8] = {w0, w1, w2, w3, w4, w5, w6, w7};
  const float* s = srcs[blockIdx.y];
  bf16* d = dst + (size_t)blockIdx.y * 589824;
  const int i = (blockIdx.x * 256 + threadIdx.x) * 8;
  floatx4 s0 = *(const floatx4*)(s + i);
  floatx4 s1 = *(const floatx4*)(s + i + 4);
  bf16x8 v;
#pragma unroll
  for (int k = 0; k < 4; k++) { v[k] = (bf16)s0[k]; v[k + 4] = (bf16)s1[k]; }
  *(bf16x8*)(d + i) = v;
}

// transpose Wo_s fp32 [768][768] -> bf16 [768][768] (out[x][y] = in[y][x])
__global__ __launch_bounds__(256) void wtrans(const float* __restrict__ in,
                                              bf16* __restrict__ out) {
  __shared__ float Ts[64][65];
  const int X0 = blockIdx.x * 64, Y0 = blockIdx.y * 64;
  const int r = threadIdx.x >> 2;
  const int c4 = (threadIdx.x & 3) * 16;
  const float* src = in + (size_t)(Y0 + r) * DD + X0 + c4;
#pragma unroll
  for (int k = 0; k < 16; k += 4) {
    floatx4 v = *(const floatx4*)(src + k);
    Ts[r][c4 + k] = v[0]; Ts[r][c4 + k + 1] = v[1];
    Ts[r][c4 + k + 2] = v[2]; Ts[r][c4 + k + 3] = v[3];
  }
  __syncthreads();
  bf16 o[16];
#pragma unroll
  for (int k = 0; k < 16; k++) o[k] = (bf16)Ts[c4 + k][r];
  *(bf16x8*)(out + (size_t)(X0 + r) * DD + Y0 + c4) = *(bf16x8*)&o[0];
  *(bf16x8*)(out + (size_t)(X0 + r) * DD + Y0 + c4 + 8) = *(bf16x8*)&o[8];
}

// ------------------------------------------------ batched LayerNorm (bf16, in place)
__device__ __forceinline__ void ln_row(bf16* x, const float* g, int lane) {
  float v[12], s = 0.f, ss = 0.f;
#pragma unroll
  for (int j = 0; j < 3; j++) {
    bf16x4 b = *(const bf16x4*)&x[j * 256 + lane * 4];
#pragma unroll
    for (int e = 0; e < 4; e++) {
      float t = (float)b[e];
      v[j * 4 + e] = t; s += t; ss += t * t;
    }
  }
#pragma unroll
  for (int o = 32; o > 0; o >>= 1) { s += __shfl_xor(s, o); ss += __shfl_xor(ss, o); }
  const float mean = s * (1.0f / DD);
  const float inv = rsqrtf(ss * (1.0f / DD) - mean * mean + 1e-6f);
#pragma unroll
  for (int j = 0; j < 3; j++) {
    floatx4 gg = *(const floatx4*)&g[j * 256 + lane * 4];
    bf16x4 o4;
#pragma unroll
    for (int e = 0; e < 4; e++) o4[e] = (bf16)((v[j * 4 + e] - mean) * inv * gg[e]);
    *(bf16x4*)&x[j * 256 + lane * 4] = o4;
  }
}

__global__ __launch_bounds__(256) void ln_all(bf16* X0, const float* g0,
                                              bf16* X1, const float* g1,
                                              bf16* X2, const float* g2,
                                              bf16* X3, const float* g3) {
  const int b = blockIdx.x;
  bf16* X; const float* g; int base;
  if (b < 4096)      { X = X0; g = g0; base = b; }
  else if (b < 8192) { X = X1; g = g1; base = b - 4096; }
  else if (b < 9216) { X = X2; g = g2; base = b - 8192; }
  else               { X = X3; g = g3; base = b - 9216; }
  const int w = threadIdx.x >> 6, lane = threadIdx.x & 63;
  ln_row(X + (size_t)(base * 4 + w) * DD, g, lane);
}

// ------------------------------------------------ GEMM core  C = A @ W^T  (m97 structure)
template <int MODE>
__device__ __forceinline__ void gemm_core(const bf16* __restrict__ A,
                                          const bf16* __restrict__ W,
                                          bf16* __restrict__ Cb,
                                          float* __restrict__ Cf,
                                          const float* __restrict__ addsrc,
                                          bf16* As, bf16* Ws) {
  const int tid = threadIdx.x;
  const int lane = tid & 63;
  const int w = tid >> 6;
  const int row0 = blockIdx.x * 128;
  const int col0 = blockIdx.y * 128;
  const int wm = (w & 1) * 64;
  const int wn = (w >> 1) * 64;
  const int fr = lane & 15;
  const int quad = lane >> 4;
  const int srow = tid >> 2;
  const int scol = (tid & 3) * 8;
  const bf16* Ag = A + (size_t)(row0 + srow) * DD + scol;
  const bf16* Wg = W + (size_t)(col0 + srow) * DD + scol;
  bf16* AsD = &As[tid * 8];
  bf16* WsD = &Ws[tid * 8];

  floatx4 acc[4][4];
#pragma unroll
  for (int i = 0; i < 4; i++)
#pragma unroll
    for (int j = 0; j < 4; j++) acc[i][j] = (floatx4){0, 0, 0, 0};

  for (int k0 = 0; k0 < DD; k0 += 32) {
    __syncthreads();
    gl2lds16(Ag + k0, AsD);
    gl2lds16(Ag + k0 + (size_t)64 * DD, AsD + 2048);
    gl2lds16(Wg + k0, WsD);
    gl2lds16(Wg + k0 + (size_t)64 * DD, WsD + 2048);
    __syncthreads();
    bf16x8 af[4], bfr[4];
#pragma unroll
    for (int i = 0; i < 4; i++)
      af[i] = *(const bf16x8*)&As[(wm + i * 16 + fr) * 32 + quad * 8];
#pragma unroll
    for (int j = 0; j < 4; j++)
      bfr[j] = *(const bf16x8*)&Ws[(wn + j * 16 + fr) * 32 + quad * 8];
#pragma unroll
    for (int i = 0; i < 4; i++)
#pragma unroll
      for (int j = 0; j < 4; j++)
        acc[i][j] = __builtin_amdgcn_mfma_f32_16x16x32_bf16(af[i], bfr[j], acc[i][j], 0, 0, 0);
  }
#pragma unroll
  for (int i = 0; i < 4; i++)
#pragma unroll
    for (int j = 0; j < 4; j++)
#pragma unroll
      for (int r = 0; r < 4; r++) {
        const int row = row0 + wm + i * 16 + quad * 4 + r;
        const int col = col0 + wn + j * 16 + fr;
        const size_t idx = (size_t)row * DD + col;
        if (MODE == 0) Cb[idx] = (bf16)acc[i][j][r];
        else Cf[idx] = acc[i][j][r] + addsrc[idx];
      }
}

__global__ __launch_bounds__(256) void gemm_b(const bf16* A, const bf16* W, bf16* C) {
  __shared__ bf16 As[4096], Ws[4096];
  gemm_core<0>(A, W, C, nullptr, nullptr, As, Ws);
}

__global__ __launch_bounds__(256) void gemm_b2(const bf16* A0, const bf16* W0, bf16* C0,
                                               const bf16* A1, const bf16* W1, bf16* C1) {
  __shared__ bf16 As[4096], Ws[4096];
  if (blockIdx.z == 0) gemm_core<0>(A0, W0, C0, nullptr, nullptr, As, Ws);
  else                 gemm_core<0>(A1, W1, C1, nullptr, nullptr, As, Ws);
}

__global__ __launch_bounds__(256) void gemm_b3(const bf16* A0, const bf16* W0, bf16* C0,
                                               const bf16* A1, const bf16* W1, bf16* C1,
                                               const bf16* A2, const bf16* W2, bf16* C2) {
  __shared__ bf16 As[4096], Ws[4096];
  if (blockIdx.z == 0)      gemm_core<0>(A0, W0, C0, nullptr, nullptr, As, Ws);
  else if (blockIdx.z == 1) gemm_core<0>(A1, W1, C1, nullptr, nullptr, As, Ws);
  else                      gemm_core<0>(A2, W2, C2, nullptr, nullptr, As, Ws);
}

__global__ __launch_bounds__(256) void gemm_final(const bf16* A, const bf16* W,
                                                  float* C, const float* addsrc) {
  __shared__ bf16 As[4096], Ws[4096];
  gemm_core<1>(A, W, nullptr, C, addsrc, As, Ws);
}

// ------------------------------------------------ fused attention, 512 threads
// 2 query-groups of 64 rows share one K/V stage. No-max softmax (scores bounded):
// p = exp(s), l accumulated per-lane, reduced once at the end.
// SPLIT: write unnormalized O partial (bf16) + l per row. grid b = (sp*npq+qt)*128 + t*8 + h.
template <int SPLIT>
__global__ __launch_bounds__(512, 4) void attn512(
    const bf16* __restrict__ Qb, const bf16* __restrict__ Kb,
    const bf16* __restrict__ Vb, bf16* __restrict__ Ob,
    float* __restrict__ Ml,
    const float* __restrict__ qpos, int qpos_ts,
    const float* __restrict__ kpos, int kpos_ts,
    int nq, int nk, int npq, int nsp) {
  const int b = blockIdx.x;
  const int h = b & 7;
  const int t = (b >> 3) & 15;
  const int rest = b >> 7;
  const int qt = rest % npq;
  const int sp = rest / npq;
  const int klen = nk / nsp;
  const int k0s = sp * klen;
  const int q0 = qt * 128;
  const bf16* Q = Qb + (size_t)t * nq * DD + h * HDIM;
  const bf16* K = Kb + (size_t)t * nk * DD + h * HDIM;
  const bf16* V = Vb + (size_t)t * nk * DD + h * HDIM;
  bf16* O = Ob + (size_t)(SPLIT ? (sp * 16 + t) : t) * nq * DD + h * HDIM;
  const float* qp = qpos + (size_t)t * qpos_ts;
  const float* kp = kpos + (size_t)t * kpos_ts;

  __shared__ bf16 Ks[64 * 104];       // [n][k] stride 104
  __shared__ bf16 Vt[96 * 72];        // [d][n] stride 72
  __shared__ bf16 Ps[2 * 64 * 72];    // per-group [m][n]

  const int tid = threadIdx.x;
  const int w = tid >> 6;
  const int g = w >> 2;           // query group 0/1
  const int wl = w & 3;           // wave in group
  const int lane = tid & 63;
  const int fr = lane & 15;
  const int quad = lane >> 4;
  const int rowb = wl * 16;
  const int qgb = q0 + g * 64;    // group's first query row
  bf16* Pg = &Ps[g * 64 * 72];

  // Q fragments (A-layout: A[m=lane&15][k=quad*8+j])
  bf16x8 qf[3];
  {
    const bf16* qrow = Q + (size_t)(qgb + rowb + fr) * DD;
#pragma unroll
    for (int c = 0; c < 3; c++) qf[c] = *(const bf16x8*)(qrow + c * 32 + quad * 8);
  }
  float qx[4], qy[4];
#pragma unroll
  for (int r = 0; r < 4; r++) {
    int qi = qgb + rowb + quad * 4 + r;
    qx[r] = qp[qi * 2];
    qy[r] = qp[qi * 2 + 1];
  }

  float lrow[4] = {0.f, 0.f, 0.f, 0.f};
  floatx4 oacc[6];
#pragma unroll
  for (int d = 0; d < 6; d++) oacc[d] = (floatx4){0, 0, 0, 0};

  // staging maps (512 threads)
  const int krA = tid >> 3, kcA = (tid & 7) * 8;             // K cols 0-63
  const int krB = (tid & 255) >> 2, kcB = 64 + (tid & 3) * 8;  // K cols 64-95 (tid<256)
  const int nb = (tid & 31) * 2, db = (tid >> 5) * 6;        // V: 2n x 6d per thread

  for (int n0 = k0s; n0 < k0s + klen; n0 += 64) {
    __syncthreads();
    *(bf16x8*)&Ks[krA * 104 + kcA] =
        *(const bf16x8*)(K + (size_t)(n0 + krA) * DD + kcA);
    if (tid < 256)
      *(bf16x8*)&Ks[krB * 104 + kcB] =
          *(const bf16x8*)(K + (size_t)(n0 + krB) * DD + kcB);
    {  // V transpose: 2 n-rows x 6 d each
      bf16 tmp[2][6];
#pragma unroll
      for (int nn = 0; nn < 2; nn++) {
        const unsigned* vg = (const unsigned*)(V + (size_t)(n0 + nb + nn) * DD + db);
        unsigned u0 = vg[0], u1 = vg[1], u2 = vg[2];
        *(unsigned*)&tmp[nn][0] = u0;
        *(unsigned*)&tmp[nn][2] = u1;
        *(unsigned*)&tmp[nn][4] = u2;
      }
#pragma unroll
      for (int dd = 0; dd < 6; dd++) {
        bf16x2 v2 = {tmp[0][dd], tmp[1][dd]};
        *(bf16x2*)&Vt[(db + dd) * 72 + nb] = v2;
      }
    }
    __syncthreads();

    // S = Q K^T (16 rows x 64 cols per wave)
    floatx4 s4[4];
#pragma unroll
    for (int j = 0; j < 4; j++) {
      floatx4 sa = {0, 0, 0, 0};
#pragma unroll
      for (int c = 0; c < 3; c++) {
        bf16x8 kf = *(const bf16x8*)&Ks[(j * 16 + fr) * 104 + c * 32 + quad * 8];
        sa = __builtin_amdgcn_mfma_f32_16x16x32_bf16(qf[c], kf, sa, 0, 0, 0);
      }
      s4[j] = sa;
    }
    float kxx[4], kyy[4];
#pragma unroll
    for (int j = 0; j < 4; j++) {
      int ki = (n0 + j * 16 + fr) * 2;
      kxx[j] = kp[ki];
      kyy[j] = kp[ki + 1];
    }
    // p = exp(score); accumulate l; stash P
#pragma unroll
    for (int j = 0; j < 4; j++)
#pragma unroll
      for (int r = 0; r < 4; r++) {
        float dx = qx[r] - kxx[j], dy = qy[r] - kyy[j];
        float sv = s4[j][r] * ATT_SCALE - 2.0f * (dx * dx + dy * dy);
        float pv = __expf(sv);
        lrow[r] += pv;
        Pg[(rowb + quad * 4 + r) * 72 + j * 16 + fr] = (bf16)pv;
      }
    // PV (same-wave Ps round trip; no barrier needed)
    bf16x8 pf0 = *(const bf16x8*)&Pg[(rowb + fr) * 72 + quad * 8];
    bf16x8 pf1 = *(const bf16x8*)&Pg[(rowb + fr) * 72 + 32 + quad * 8];
#pragma unroll
    for (int d = 0; d < 6; d++) {
      bf16x8 v0 = *(const bf16x8*)&Vt[(d * 16 + fr) * 72 + quad * 8];
      bf16x8 v1 = *(const bf16x8*)&Vt[(d * 16 + fr) * 72 + 32 + quad * 8];
      oacc[d] = __builtin_amdgcn_mfma_f32_16x16x32_bf16(pf0, v0, oacc[d], 0, 0, 0);
      oacc[d] = __builtin_amdgcn_mfma_f32_16x16x32_bf16(pf1, v1, oacc[d], 0, 0, 0);
    }
  }

  // final l reduce across the 16 fr lanes
#pragma unroll
  for (int r = 0; r < 4; r++)
#pragma unroll
    for (int o = 1; o < 16; o <<= 1) lrow[r] += __shfl_xor(lrow[r], o);

#pragma unroll
  for (int r = 0; r < 4; r++) {
    int row = qgb + rowb + quad * 4 + r;
    if (SPLIT) {
#pragma unroll
      for (int d = 0; d < 6; d++)
        O[(size_t)row * DD + d * 16 + fr] = (bf16)oacc[d][r];
      if (fr == 0)
        Ml[((size_t)(sp * 16 + t) * 8 + h) * nq + row] = lrow[r];
    } else {
      float inv = 1.0f / lrow[r];
#pragma unroll
      for (int d = 0; d < 6; d++)
        O[(size_t)row * DD + d * 16 + fr] = (bf16)(oacc[d][r] * inv);
    }
  }
}

// combine 4 unnormalized split partials: Out = (ΣO_s) / (Σl_s)
__global__ __launch_bounds__(256) void combine4(const bf16* __restrict__ Op,
                                                const float* __restrict__ Ml,
                                                bf16* __restrict__ Out) {
  const int row = blockIdx.x;  // t*256 + q
  const int t = row >> 8;
  const int q = row & 255;
#pragma unroll
  for (int e = 0; e < 3; e++) {
    int dim = threadIdx.x + e * 256;
    int hh = dim / 96;
    float osum = 0.f, lsum = 0.f;
#pragma unroll
    for (int s = 0; s < 4; s++) {
      lsum += Ml[((size_t)(s * 16 + t) * 8 + hh) * 256 + q];
      osum += (float)Op[((size_t)(s * 16 + t) * 256 + q) * DD + dim];
    }
    Out[(size_t)row * DD + dim] = (bf16)(osum / lsum);
  }
}

// ------------------------------------------------ launch
extern "C" void kernel_launch(void* const* d_in, const int* in_sizes, int n_in,
                              void* d_out, int out_size, void* d_ws, size_t ws_size,
                              hipStream_t stream) {
  const float* features = (const float*)d_in[0];
  const float* tracks   = (const float*)d_in[1];
  const float* fpos     = (const float*)d_in[2];
  const float* tpe      = (const float*)d_in[3];
  const float* fpe      = (const float*)d_in[4];
  const float* Wq_s     = (const float*)d_in[5];
  const float* Wk_s     = (const float*)d_in[6];
  const float* Wv_s     = (const float*)d_in[7];
  const float* qg_s     = (const float*)d_in[8];
  const float* kg_s     = (const float*)d_in[9];
  const float* Wo_s     = (const float*)d_in[10];
  const float* Wq_p     = (const float*)d_in[11];
  const float* Wk_p     = (const float*)d_in[12];
  const float* Wv_p     = (const float*)d_in[13];
  const float* qg_p     = (const float*)d_in[14];
  const float* kg_p     = (const float*)d_in[15];
  const float* Wout_p   = (const float*)d_in[16];
  float* out = (float*)d_out;

  const size_t SB = (size_t)16 * 1024 * 768;
  const size_t SS = (size_t)16 * 256 * 768;
  const size_t SW = (size_t)768 * 768;
  bf16* p = (bf16*)d_ws;
  bf16* Fb  = p; p += SB;     // features bf16 (reused as U after big GEMMs)
  bf16* Xb  = p; p += SB;     // features+fpe
  bf16* Feb = p; p += SB;     // fpe bf16
  bf16* Kc  = p; p += SB;     // K_s
  bf16* Vc  = p; p += SB;     // V_s
  bf16* Qb2 = p; p += SB;     // Q2 (splatting queries)
  bf16* Tb  = p; p += SS;     // tpe bf16
  bf16* Qc  = p; p += SS;     // Q_s (reused as V2 after sampling attn)
  bf16* K2  = p; p += SS;     // K2
  bf16* Sh  = p; p += SS;     // sampled heads (combine output)
  bf16* Op  = p; p += 4 * SS; // split-K partial O (unnormalized)
  bf16* Wb  = p; p += 8 * SW; // 8 weights bf16
  bf16* WoT = p; p += SW;     // Wo_s^T bf16
  bf16* Wcr = p; p += SW;     // Wv_p @ Wo_s  bf16
  float* Ml = (float*)p;      // split-K l: 4*16*8*256 floats
  bf16* V2 = Qc; bf16* U = Fb;

  dim3 blk(256);

  conv_fuse<<<6144, blk, 0, stream>>>(features, fpe, Fb, Xb, Feb);
  f2b<<<1536, blk, 0, stream>>>(tpe, Tb);
  wconv<<<dim3(288, 8), blk, 0, stream>>>(Wq_s, Wk_s, Wv_s, Wo_s,
                                          Wq_p, Wk_p, Wv_p, Wout_p, Wb);
  wtrans<<<dim3(12, 12), blk, 0, stream>>>(Wo_s, WoT);
  // Wcr = Wv_p @ Wo_s  (so V2 = Sh @ Wcr^T folds two small GEMMs)
  gemm_b<<<dim3(6, 6), blk, 0, stream>>>(Wb + 6 * SW, WoT, Wcr);
  // three big GEMMs batched: K_s, V_s, Q2
  gemm_b3<<<dim3(128, 6, 3), blk, 0, stream>>>(Xb, Wb + 1 * SW, Kc,
                                               Fb, Wb + 2 * SW, Vc,
                                               Feb, Wb + 4 * SW, Qb2);
  // small GEMMs: Q_s and K2 batched
  gemm_b2<<<dim3(32, 6, 2), blk, 0, stream>>>(Tb, Wb + 0 * SW, Qc,
                                              Tb, Wb + 5 * SW, K2);
  // all four LayerNorms
  ln_all<<<10240, blk, 0, stream>>>(Kc, kg_s, Qb2, qg_p, Qc, qg_s, K2, kg_p);
  // sampling: tracks query pixels, split-K x4 (nq=256, nk=1024, npq=2)
  attn512<1><<<1024, dim3(512), 0, stream>>>(Qc, Kc, Vc, Op, Ml,
                                             tracks, 512, fpos, 0, 256, 1024, 2, 4);
  combine4<<<4096, blk, 0, stream>>>(Op, Ml, Sh);
  // V2 = Sh @ Wcr^T  (folded sampled/Wv_p GEMM)
  gemm_b<<<dim3(32, 6), blk, 0, stream>>>(Sh, Wcr, V2);
  // splatting: pixels query tracks (nq=1024, nk=256, npq=8, no split)
  attn512<0><<<1024, dim3(512), 0, stream>>>(Qb2, K2, V2, U, nullptr,
                                             fpos, 0, tracks, 512, 1024, 256, 8, 1);
  gemm_final<<<dim3(128, 6), blk, 0, stream>>>(U, Wb + 7 * SW, out, features);
}

// Round 5
// 475.167 us; speedup vs baseline: 1.1362x; 1.0342x over previous
//
#include <hip/hip_runtime.h>

#define DD 768
#define HDIM 96
#define ATT_SCALE 0.10206207261596575f  // 1/sqrt(96)

typedef float floatx4 __attribute__((ext_vector_type(4)));
typedef __bf16 bf16;
typedef bf16 bf16x8 __attribute__((ext_vector_type(8)));
typedef bf16 bf16x4 __attribute__((ext_vector_type(4)));
typedef bf16 bf16x2 __attribute__((ext_vector_type(2)));

__device__ __forceinline__ void gl2lds16(const bf16* g, bf16* l) {
  __builtin_amdgcn_global_load_lds(
      (const __attribute__((address_space(1))) void*)g,
      (__attribute__((address_space(3))) void*)l, 16, 0, 0);
}

// ------------------------------------------------ merged prep kernel
// b<6144: conv_fuse | <7680: f2b(tpe) | <9984: wconv x8 | <10128: wtrans(Wo_s)
__global__ __launch_bounds__(256) void prep(
    const float* __restrict__ features, const float* __restrict__ fpe,
    const float* __restrict__ tpe,
    const float* w0, const float* w1, const float* w2, const float* w3,
    const float* w4, const float* w5, const float* w6, const float* w7,
    bf16* __restrict__ Fb, bf16* __restrict__ Xb, bf16* __restrict__ Feb,
    bf16* __restrict__ Tb, bf16* __restrict__ Wb, bf16* __restrict__ WoT) {
  const int b = blockIdx.x;
  const int tid = threadIdx.x;
  if (b < 6144) {
    const int i = (b * 256 + tid) * 8;
    floatx4 f0 = *(const floatx4*)(features + i);
    floatx4 f1 = *(const floatx4*)(features + i + 4);
    floatx4 e0 = *(const floatx4*)(fpe + i);
    floatx4 e1 = *(const floatx4*)(fpe + i + 4);
    bf16x8 fv, xv, ev;
#pragma unroll
    for (int k = 0; k < 4; k++) {
      fv[k] = (bf16)f0[k];           fv[k + 4] = (bf16)f1[k];
      ev[k] = (bf16)e0[k];           ev[k + 4] = (bf16)e1[k];
      xv[k] = (bf16)(f0[k] + e0[k]); xv[k + 4] = (bf16)(f1[k] + e1[k]);
    }
    *(bf16x8*)(Fb + i) = fv;
    *(bf16x8*)(Xb + i) = xv;
    *(bf16x8*)(Feb + i) = ev;
  } else if (b < 7680) {
    const int i = ((b - 6144) * 256 + tid) * 8;
    floatx4 s0 = *(const floatx4*)(tpe + i);
    floatx4 s1 = *(const floatx4*)(tpe + i + 4);
    bf16x8 v;
#pragma unroll
    for (int k = 0; k < 4; k++) { v[k] = (bf16)s0[k]; v[k + 4] = (bf16)s1[k]; }
    *(bf16x8*)(Tb + i) = v;
  } else if (b < 9984) {
    const int sub = b - 7680;
    const int wi = sub / 288, xb = sub % 288;
    const float* srcs[8] = {w0, w1, w2, w3, w4, w5, w6, w7};
    const float* s = srcs[wi];
    bf16* d = Wb + (size_t)wi * 589824;
    const int i = (xb * 256 + tid) * 8;
    floatx4 s0 = *(const floatx4*)(s + i);
    floatx4 s1 = *(const floatx4*)(s + i + 4);
    bf16x8 v;
#pragma unroll
    for (int k = 0; k < 4; k++) { v[k] = (bf16)s0[k]; v[k + 4] = (bf16)s1[k]; }
    *(bf16x8*)(d + i) = v;
  } else {
    // transpose Wo_s -> WoT bf16
    __shared__ float Ts[64][65];
    const int sub = b - 9984;
    const int X0 = (sub % 12) * 64, Y0 = (sub / 12) * 64;
    const int r = tid >> 2;
    const int c4 = (tid & 3) * 16;
    const float* src = w3 + (size_t)(Y0 + r) * DD + X0 + c4;  // w3 == Wo_s
#pragma unroll
    for (int k = 0; k < 16; k += 4) {
      floatx4 v = *(const floatx4*)(src + k);
      Ts[r][c4 + k] = v[0]; Ts[r][c4 + k + 1] = v[1];
      Ts[r][c4 + k + 2] = v[2]; Ts[r][c4 + k + 3] = v[3];
    }
    __syncthreads();
    bf16 o[16];
#pragma unroll
    for (int k = 0; k < 16; k++) o[k] = (bf16)Ts[c4 + k][r];
    *(bf16x8*)(WoT + (size_t)(X0 + r) * DD + Y0 + c4) = *(bf16x8*)&o[0];
    *(bf16x8*)(WoT + (size_t)(X0 + r) * DD + Y0 + c4 + 8) = *(bf16x8*)&o[8];
  }
}

// ------------------------------------------------ batched LayerNorm (bf16, in place)
__device__ __forceinline__ void ln_row(bf16* x, const float* g, int lane) {
  float v[12], s = 0.f, ss = 0.f;
#pragma unroll
  for (int j = 0; j < 3; j++) {
    bf16x4 b = *(const bf16x4*)&x[j * 256 + lane * 4];
#pragma unroll
    for (int e = 0; e < 4; e++) {
      float t = (float)b[e];
      v[j * 4 + e] = t; s += t; ss += t * t;
    }
  }
#pragma unroll
  for (int o = 32; o > 0; o >>= 1) { s += __shfl_xor(s, o); ss += __shfl_xor(ss, o); }
  const float mean = s * (1.0f / DD);
  const float inv = rsqrtf(ss * (1.0f / DD) - mean * mean + 1e-6f);
#pragma unroll
  for (int j = 0; j < 3; j++) {
    floatx4 gg = *(const floatx4*)&g[j * 256 + lane * 4];
    bf16x4 o4;
#pragma unroll
    for (int e = 0; e < 4; e++) o4[e] = (bf16)((v[j * 4 + e] - mean) * inv * gg[e]);
    *(bf16x4*)&x[j * 256 + lane * 4] = o4;
  }
}

__global__ __launch_bounds__(256) void ln_all(bf16* X0, const float* g0,
                                              bf16* X1, const float* g1,
                                              bf16* X2, const float* g2,
                                              bf16* X3, const float* g3) {
  const int b = blockIdx.x;
  bf16* X; const float* g; int base;
  if (b < 4096)      { X = X0; g = g0; base = b; }
  else if (b < 8192) { X = X1; g = g1; base = b - 4096; }
  else if (b < 9216) { X = X2; g = g2; base = b - 8192; }
  else               { X = X3; g = g3; base = b - 9216; }
  const int w = threadIdx.x >> 6, lane = threadIdx.x & 63;
  ln_row(X + (size_t)(base * 4 + w) * DD, g, lane);
}

// ------------------------------------------------ GEMM core, BK=64
// Two unpadded [128][32] LDS buffers per operand per iter (keeps m97 bank pattern).
// MODE 0: C bf16. MODE 1: C fp32 = acc + addsrc.
template <int MODE>
__device__ __forceinline__ void gemm_core64(const bf16* __restrict__ A,
                                            const bf16* __restrict__ W,
                                            bf16* __restrict__ Cb,
                                            float* __restrict__ Cf,
                                            const float* __restrict__ addsrc,
                                            bf16* As, bf16* Ws,
                                            int row0, int col0) {
  const int tid = threadIdx.x;
  const int lane = tid & 63;
  const int w = tid >> 6;
  const int wm = (w & 1) * 64;
  const int wn = (w >> 1) * 64;
  const int fr = lane & 15;
  const int quad = lane >> 4;
  const int srow = tid >> 2;
  const int scol = (tid & 3) * 8;
  const bf16* Ag = A + (size_t)(row0 + srow) * DD + scol;
  const bf16* Wg = W + (size_t)(col0 + srow) * DD + scol;
  bf16* AsD = &As[tid * 8];
  bf16* WsD = &Ws[tid * 8];

  floatx4 acc[4][4];
#pragma unroll
  for (int i = 0; i < 4; i++)
#pragma unroll
    for (int j = 0; j < 4; j++) acc[i][j] = (floatx4){0, 0, 0, 0};

  for (int k0 = 0; k0 < DD; k0 += 64) {
    __syncthreads();
    // k-low half -> buffer 0
    gl2lds16(Ag + k0, AsD);
    gl2lds16(Ag + k0 + (size_t)64 * DD, AsD + 2048);
    gl2lds16(Wg + k0, WsD);
    gl2lds16(Wg + k0 + (size_t)64 * DD, WsD + 2048);
    // k-high half -> buffer 1
    gl2lds16(Ag + k0 + 32, AsD + 4096);
    gl2lds16(Ag + k0 + 32 + (size_t)64 * DD, AsD + 4096 + 2048);
    gl2lds16(Wg + k0 + 32, WsD + 4096);
    gl2lds16(Wg + k0 + 32 + (size_t)64 * DD, WsD + 4096 + 2048);
    __syncthreads();
#pragma unroll
    for (int half = 0; half < 2; half++) {
      const bf16* Ah = As + half * 4096;
      const bf16* Wh = Ws + half * 4096;
      bf16x8 af[4], bfr[4];
#pragma unroll
      for (int i = 0; i < 4; i++)
        af[i] = *(const bf16x8*)&Ah[(wm + i * 16 + fr) * 32 + quad * 8];
#pragma unroll
      for (int j = 0; j < 4; j++)
        bfr[j] = *(const bf16x8*)&Wh[(wn + j * 16 + fr) * 32 + quad * 8];
#pragma unroll
      for (int i = 0; i < 4; i++)
#pragma unroll
        for (int j = 0; j < 4; j++)
          acc[i][j] = __builtin_amdgcn_mfma_f32_16x16x32_bf16(af[i], bfr[j], acc[i][j], 0, 0, 0);
    }
  }
#pragma unroll
  for (int i = 0; i < 4; i++)
#pragma unroll
    for (int j = 0; j < 4; j++)
#pragma unroll
      for (int r = 0; r < 4; r++) {
        const int row = row0 + wm + i * 16 + quad * 4 + r;
        const int col = col0 + wn + j * 16 + fr;
        const size_t idx = (size_t)row * DD + col;
        if (MODE == 0) Cb[idx] = (bf16)acc[i][j][r];
        else Cf[idx] = acc[i][j][r] + addsrc[idx];
      }
}

// one launch: z=0..2 big GEMMs; z=3: x<32 Qs, x<64 K2, x<70 Wcr, else idle
__global__ __launch_bounds__(256) void gemm_all(
    const bf16* Xb, const bf16* Fb, const bf16* Feb, const bf16* Tb,
    const bf16* Wb, const bf16* WoT,
    bf16* Kc, bf16* Vc, bf16* Qb2, bf16* Qc, bf16* K2, bf16* Wcr) {
  __shared__ bf16 As[8192], Ws[8192];
  const size_t SW = (size_t)768 * 768;
  const int z = blockIdx.z;
  if (z == 0)
    gemm_core64<0>(Xb, Wb + 1 * SW, Kc, nullptr, nullptr, As, Ws,
                   blockIdx.x * 128, blockIdx.y * 128);
  else if (z == 1)
    gemm_core64<0>(Fb, Wb + 2 * SW, Vc, nullptr, nullptr, As, Ws,
                   blockIdx.x * 128, blockIdx.y * 128);
  else if (z == 2)
    gemm_core64<0>(Feb, Wb + 4 * SW, Qb2, nullptr, nullptr, As, Ws,
                   blockIdx.x * 128, blockIdx.y * 128);
  else {
    const int x = blockIdx.x;
    if (x < 32)
      gemm_core64<0>(Tb, Wb + 0 * SW, Qc, nullptr, nullptr, As, Ws,
                     x * 128, blockIdx.y * 128);
    else if (x < 64)
      gemm_core64<0>(Tb, Wb + 5 * SW, K2, nullptr, nullptr, As, Ws,
                     (x - 32) * 128, blockIdx.y * 128);
    else if (x < 70)
      gemm_core64<0>(Wb + 6 * SW, WoT, Wcr, nullptr, nullptr, As, Ws,
                     (x - 64) * 128, blockIdx.y * 128);
  }
}

__global__ __launch_bounds__(256) void gemm_b(const bf16* A, const bf16* W, bf16* C) {
  __shared__ bf16 As[8192], Ws[8192];
  gemm_core64<0>(A, W, C, nullptr, nullptr, As, Ws, blockIdx.x * 128, blockIdx.y * 128);
}

__global__ __launch_bounds__(256) void gemm_final(const bf16* A, const bf16* W,
                                                  float* C, const float* addsrc) {
  __shared__ bf16 As[8192], Ws[8192];
  gemm_core64<1>(A, W, nullptr, C, addsrc, As, Ws, blockIdx.x * 128, blockIdx.y * 128);
}

// ------------------------------------------------ fused attention, 512 threads
// 2 query-groups of 64 rows share one K/V stage. No-max softmax (scores bounded).
// SPLIT: write unnormalized O partial (bf16) + l per row. grid b = (sp*npq+qt)*128 + t*8 + h.
template <int SPLIT>
__global__ __launch_bounds__(512, 4) void attn512(
    const bf16* __restrict__ Qb, const bf16* __restrict__ Kb,
    const bf16* __restrict__ Vb, bf16* __restrict__ Ob,
    float* __restrict__ Ml,
    const float* __restrict__ qpos, int qpos_ts,
    const float* __restrict__ kpos, int kpos_ts,
    int nq, int nk, int npq, int nsp) {
  const int b = blockIdx.x;
  const int h = b & 7;
  const int t = (b >> 3) & 15;
  const int rest = b >> 7;
  const int qt = rest % npq;
  const int sp = rest / npq;
  const int klen = nk / nsp;
  const int k0s = sp * klen;
  const int q0 = qt * 128;
  const bf16* Q = Qb + (size_t)t * nq * DD + h * HDIM;
  const bf16* K = Kb + (size_t)t * nk * DD + h * HDIM;
  const bf16* V = Vb + (size_t)t * nk * DD + h * HDIM;
  bf16* O = Ob + (size_t)(SPLIT ? (sp * 16 + t) : t) * nq * DD + h * HDIM;
  const float* qp = qpos + (size_t)t * qpos_ts;
  const float* kp = kpos + (size_t)t * kpos_ts;

  __shared__ bf16 Ks[64 * 104];       // [n][k] stride 104
  __shared__ bf16 Vt[96 * 72];        // [d][n] stride 72
  __shared__ bf16 Ps[2 * 64 * 72];    // per-group [m][n]

  const int tid = threadIdx.x;
  const int w = tid >> 6;
  const int g = w >> 2;
  const int wl = w & 3;
  const int lane = tid & 63;
  const int fr = lane & 15;
  const int quad = lane >> 4;
  const int rowb = wl * 16;
  const int qgb = q0 + g * 64;
  bf16* Pg = &Ps[g * 64 * 72];

  bf16x8 qf[3];
  {
    const bf16* qrow = Q + (size_t)(qgb + rowb + fr) * DD;
#pragma unroll
    for (int c = 0; c < 3; c++) qf[c] = *(const bf16x8*)(qrow + c * 32 + quad * 8);
  }
  float qx[4], qy[4];
#pragma unroll
  for (int r = 0; r < 4; r++) {
    int qi = qgb + rowb + quad * 4 + r;
    qx[r] = qp[qi * 2];
    qy[r] = qp[qi * 2 + 1];
  }

  float lrow[4] = {0.f, 0.f, 0.f, 0.f};
  floatx4 oacc[6];
#pragma unroll
  for (int d = 0; d < 6; d++) oacc[d] = (floatx4){0, 0, 0, 0};

  const int krA = tid >> 3, kcA = (tid & 7) * 8;
  const int krB = (tid & 255) >> 2, kcB = 64 + (tid & 3) * 8;
  const int nb = (tid & 31) * 2, db = (tid >> 5) * 6;

  for (int n0 = k0s; n0 < k0s + klen; n0 += 64) {
    __syncthreads();
    *(bf16x8*)&Ks[krA * 104 + kcA] =
        *(const bf16x8*)(K + (size_t)(n0 + krA) * DD + kcA);
    if (tid < 256)
      *(bf16x8*)&Ks[krB * 104 + kcB] =
          *(const bf16x8*)(K + (size_t)(n0 + krB) * DD + kcB);
    {
      bf16 tmp[2][6];
#pragma unroll
      for (int nn = 0; nn < 2; nn++) {
        const unsigned* vg = (const unsigned*)(V + (size_t)(n0 + nb + nn) * DD + db);
        unsigned u0 = vg[0], u1 = vg[1], u2 = vg[2];
        *(unsigned*)&tmp[nn][0] = u0;
        *(unsigned*)&tmp[nn][2] = u1;
        *(unsigned*)&tmp[nn][4] = u2;
      }
#pragma unroll
      for (int dd = 0; dd < 6; dd++) {
        bf16x2 v2 = {tmp[0][dd], tmp[1][dd]};
        *(bf16x2*)&Vt[(db + dd) * 72 + nb] = v2;
      }
    }
    __syncthreads();

    floatx4 s4[4];
#pragma unroll
    for (int j = 0; j < 4; j++) {
      floatx4 sa = {0, 0, 0, 0};
#pragma unroll
      for (int c = 0; c < 3; c++) {
        bf16x8 kf = *(const bf16x8*)&Ks[(j * 16 + fr) * 104 + c * 32 + quad * 8];
        sa = __builtin_amdgcn_mfma_f32_16x16x32_bf16(qf[c], kf, sa, 0, 0, 0);
      }
      s4[j] = sa;
    }
    float kxx[4], kyy[4];
#pragma unroll
    for (int j = 0; j < 4; j++) {
      int ki = (n0 + j * 16 + fr) * 2;
      kxx[j] = kp[ki];
      kyy[j] = kp[ki + 1];
    }
#pragma unroll
    for (int j = 0; j < 4; j++)
#pragma unroll
      for (int r = 0; r < 4; r++) {
        float dx = qx[r] - kxx[j], dy = qy[r] - kyy[j];
        float sv = s4[j][r] * ATT_SCALE - 2.0f * (dx * dx + dy * dy);
        float pv = __expf(sv);
        lrow[r] += pv;
        Pg[(rowb + quad * 4 + r) * 72 + j * 16 + fr] = (bf16)pv;
      }
    bf16x8 pf0 = *(const bf16x8*)&Pg[(rowb + fr) * 72 + quad * 8];
    bf16x8 pf1 = *(const bf16x8*)&Pg[(rowb + fr) * 72 + 32 + quad * 8];
#pragma unroll
    for (int d = 0; d < 6; d++) {
      bf16x8 v0 = *(const bf16x8*)&Vt[(d * 16 + fr) * 72 + quad * 8];
      bf16x8 v1 = *(const bf16x8*)&Vt[(d * 16 + fr) * 72 + 32 + quad * 8];
      oacc[d] = __builtin_amdgcn_mfma_f32_16x16x32_bf16(pf0, v0, oacc[d], 0, 0, 0);
      oacc[d] = __builtin_amdgcn_mfma_f32_16x16x32_bf16(pf1, v1, oacc[d], 0, 0, 0);
    }
  }

#pragma unroll
  for (int r = 0; r < 4; r++)
#pragma unroll
    for (int o = 1; o < 16; o <<= 1) lrow[r] += __shfl_xor(lrow[r], o);

#pragma unroll
  for (int r = 0; r < 4; r++) {
    int row = qgb + rowb + quad * 4 + r;
    if (SPLIT) {
#pragma unroll
      for (int d = 0; d < 6; d++)
        O[(size_t)row * DD + d * 16 + fr] = (bf16)oacc[d][r];
      if (fr == 0)
        Ml[((size_t)(sp * 16 + t) * 8 + h) * nq + row] = lrow[r];
    } else {
      float inv = 1.0f / lrow[r];
#pragma unroll
      for (int d = 0; d < 6; d++)
        O[(size_t)row * DD + d * 16 + fr] = (bf16)(oacc[d][r] * inv);
    }
  }
}

// combine 4 unnormalized split partials: Out = (ΣO_s) / (Σl_s)
__global__ __launch_bounds__(256) void combine4(const bf16* __restrict__ Op,
                                                const float* __restrict__ Ml,
                                                bf16* __restrict__ Out) {
  const int row = blockIdx.x;  // t*256 + q
  const int t = row >> 8;
  const int q = row & 255;
#pragma unroll
  for (int e = 0; e < 3; e++) {
    int dim = threadIdx.x + e * 256;
    int hh = dim / 96;
    float osum = 0.f, lsum = 0.f;
#pragma unroll
    for (int s = 0; s < 4; s++) {
      lsum += Ml[((size_t)(s * 16 + t) * 8 + hh) * 256 + q];
      osum += (float)Op[((size_t)(s * 16 + t) * 256 + q) * DD + dim];
    }
    Out[(size_t)row * DD + dim] = (bf16)(osum / lsum);
  }
}

// ------------------------------------------------ launch
extern "C" void kernel_launch(void* const* d_in, const int* in_sizes, int n_in,
                              void* d_out, int out_size, void* d_ws, size_t ws_size,
                              hipStream_t stream) {
  const float* features = (const float*)d_in[0];
  const float* tracks   = (const float*)d_in[1];
  const float* fpos     = (const float*)d_in[2];
  const float* tpe      = (const float*)d_in[3];
  const float* fpe      = (const float*)d_in[4];
  const float* Wq_s     = (const float*)d_in[5];
  const float* Wk_s     = (const float*)d_in[6];
  const float* Wv_s     = (const float*)d_in[7];
  const float* qg_s     = (const float*)d_in[8];
  const float* kg_s     = (const float*)d_in[9];
  const float* Wo_s     = (const float*)d_in[10];
  const float* Wq_p     = (const float*)d_in[11];
  const float* Wk_p     = (const float*)d_in[12];
  const float* Wv_p     = (const float*)d_in[13];
  const float* qg_p     = (const float*)d_in[14];
  const float* kg_p     = (const float*)d_in[15];
  const float* Wout_p   = (const float*)d_in[16];
  float* out = (float*)d_out;

  const size_t SB = (size_t)16 * 1024 * 768;
  const size_t SS = (size_t)16 * 256 * 768;
  const size_t SW = (size_t)768 * 768;
  bf16* p = (bf16*)d_ws;
  bf16* Fb  = p; p += SB;     // features bf16 (reused as U)
  bf16* Xb  = p; p += SB;     // features+fpe
  bf16* Feb = p; p += SB;     // fpe bf16
  bf16* Kc  = p; p += SB;     // K_s
  bf16* Vc  = p; p += SB;     // V_s
  bf16* Qb2 = p; p += SB;     // Q2
  bf16* Tb  = p; p += SS;     // tpe bf16
  bf16* Qc  = p; p += SS;     // Q_s (reused as V2)
  bf16* K2  = p; p += SS;     // K2
  bf16* Sh  = p; p += SS;     // sampled heads
  bf16* Op  = p; p += 4 * SS; // split-K partial O
  bf16* Wb  = p; p += 8 * SW; // weights bf16
  bf16* WoT = p; p += SW;     // Wo_s^T
  bf16* Wcr = p; p += SW;     // Wv_p @ Wo_s
  float* Ml = (float*)p;      // split-K l
  bf16* V2 = Qc; bf16* U = Fb;

  dim3 blk(256);

  prep<<<10128, blk, 0, stream>>>(features, fpe, tpe,
                                  Wq_s, Wk_s, Wv_s, Wo_s, Wq_p, Wk_p, Wv_p, Wout_p,
                                  Fb, Xb, Feb, Tb, Wb, WoT);
  gemm_all<<<dim3(128, 6, 4), blk, 0, stream>>>(Xb, Fb, Feb, Tb, Wb, WoT,
                                                Kc, Vc, Qb2, Qc, K2, Wcr);
  ln_all<<<10240, blk, 0, stream>>>(Kc, kg_s, Qb2, qg_p, Qc, qg_s, K2, kg_p);
  attn512<1><<<1024, dim3(512), 0, stream>>>(Qc, Kc, Vc, Op, Ml,
                                             tracks, 512, fpos, 0, 256, 1024, 2, 4);
  combine4<<<4096, blk, 0, stream>>>(Op, Ml, Sh);
  gemm_b<<<dim3(32, 6), blk, 0, stream>>>(Sh, Wcr, V2);
  attn512<0><<<1024, dim3(512), 0, stream>>>(Qb2, K2, V2, U, nullptr,
                                             fpos, 0, tracks, 512, 1024, 256, 8, 1);
  gemm_final<<<dim3(128, 6), blk, 0, stream>>>(U, Wb + 7 * SW, out, features);
}